// Round 1
// baseline (2191.580 us; speedup 1.0000x reference)
//
#include <hip/hip_runtime.h>
#include <math.h>

#define EMB  256   // embedding dim
#define ATT  64    // attention dim
#define KN   16    // neighbors
#define ROWS 16    // rows per block
#define NT   256   // threads per block

__device__ __forceinline__ float dot4(float4 a, float4 b) {
    return a.x * b.x + a.y * b.y + a.z * b.z + a.w * b.w;
}

// Fused single-head neighborhood attention.
// Math restructure: scores = q . (Wk n) = (Wk^T q) . n  -> compute p = Wk^T q
// once per row (64x256 matvec) instead of projecting all 16 neighbors
// (16x 64x256 matvecs). Drops total FLOPs 54 GF -> 22.6 GF.
__global__ __launch_bounds__(NT) void fused_neigh_attn(
    const float* __restrict__ center,  // [B,256]
    const float* __restrict__ neigh,   // [B,16,256]
    const float* __restrict__ conf,    // [B,16]
    const int*   __restrict__ valid,   // [B]
    const float* __restrict__ Wq,      // [64,256]
    const float* __restrict__ Wk,      // [64,256]
    const float* __restrict__ Wg,      // [256,512]
    const float* __restrict__ Wgb,     // [256]
    float* __restrict__ out)           // [B,256]
{
    __shared__ float c_lds[ROWS][EMB];  // centers
    __shared__ float q_lds[ROWS][ATT];  // q vectors
    __shared__ float p_lds[ROWS][EMB];  // p = Wk^T q
    __shared__ float x_lds[ROWS][EMB];  // contexts

    const int t = threadIdx.x;
    const int rowBase = blockIdx.x * ROWS;
    const int lane = t & 63;
    const int rg = t >> 6;  // wave id 0..3 -> row group of 4

    // ---- Phase 0: stage 16 center rows into LDS (coalesced float4) ----
    {
        const float4* src = reinterpret_cast<const float4*>(center + (size_t)rowBase * EMB);
        float4* dst = reinterpret_cast<float4*>(&c_lds[0][0]);
        #pragma unroll
        for (int i = 0; i < (ROWS * EMB / 4) / NT; ++i)
            dst[t + i * NT] = src[t + i * NT];
    }
    __syncthreads();

    // ---- Phase Q: q[r][a] = sum_d Wq[a][d] * c[r][d]; a = lane, 4 rows per wave ----
    {
        const float4* wq = reinterpret_cast<const float4*>(Wq + (size_t)lane * EMB);
        float acc0 = 0.f, acc1 = 0.f, acc2 = 0.f, acc3 = 0.f;
        const int r0 = rg << 2;
        for (int s4 = 0; s4 < EMB / 4; ++s4) {
            const float4 w = wq[s4];
            const float4 c0 = *reinterpret_cast<const float4*>(&c_lds[r0 + 0][s4 * 4]);
            const float4 c1 = *reinterpret_cast<const float4*>(&c_lds[r0 + 1][s4 * 4]);
            const float4 c2 = *reinterpret_cast<const float4*>(&c_lds[r0 + 2][s4 * 4]);
            const float4 c3 = *reinterpret_cast<const float4*>(&c_lds[r0 + 3][s4 * 4]);
            acc0 += dot4(w, c0);
            acc1 += dot4(w, c1);
            acc2 += dot4(w, c2);
            acc3 += dot4(w, c3);
        }
        q_lds[r0 + 0][lane] = acc0;
        q_lds[r0 + 1][lane] = acc1;
        q_lds[r0 + 2][lane] = acc2;
        q_lds[r0 + 3][lane] = acc3;
    }
    __syncthreads();

    // ---- Phase P: p[r][d] = sum_a q[r][a] * Wk[a][d]; lane owns d4 = 4*lane.. ----
    {
        const int r0 = rg << 2;
        float4 acc[4];
        #pragma unroll
        for (int r = 0; r < 4; ++r) acc[r] = make_float4(0.f, 0.f, 0.f, 0.f);
        for (int a4 = 0; a4 < ATT / 4; ++a4) {
            // 4 consecutive Wk rows, coalesced float4 across lanes
            const float4 w0 = *reinterpret_cast<const float4*>(Wk + (size_t)(a4 * 4 + 0) * EMB + lane * 4);
            const float4 w1 = *reinterpret_cast<const float4*>(Wk + (size_t)(a4 * 4 + 1) * EMB + lane * 4);
            const float4 w2 = *reinterpret_cast<const float4*>(Wk + (size_t)(a4 * 4 + 2) * EMB + lane * 4);
            const float4 w3 = *reinterpret_cast<const float4*>(Wk + (size_t)(a4 * 4 + 3) * EMB + lane * 4);
            #pragma unroll
            for (int r = 0; r < 4; ++r) {
                const float4 q4 = *reinterpret_cast<const float4*>(&q_lds[r0 + r][a4 * 4]);
                acc[r].x += q4.x * w0.x + q4.y * w1.x + q4.z * w2.x + q4.w * w3.x;
                acc[r].y += q4.x * w0.y + q4.y * w1.y + q4.z * w2.y + q4.w * w3.y;
                acc[r].z += q4.x * w0.z + q4.y * w1.z + q4.z * w2.z + q4.w * w3.z;
                acc[r].w += q4.x * w0.w + q4.y * w1.w + q4.z * w2.w + q4.w * w3.w;
            }
        }
        #pragma unroll
        for (int r = 0; r < 4; ++r)
            *reinterpret_cast<float4*>(&p_lds[r0 + r][lane * 4]) = acc[r];
    }
    __syncthreads();

    // ---- Phase S: scores -> softmax -> context, wave rg handles rows rg*4..rg*4+3 ----
    #pragma unroll 1
    for (int rr = 0; rr < 4; ++rr) {
        const int r = (rg << 2) + rr;
        const int grow = rowBase + r;
        const float4 p4 = *reinterpret_cast<const float4*>(&p_lds[r][lane * 4]);
        const float4* nb = reinterpret_cast<const float4*>(neigh + (size_t)grow * (KN * EMB));
        float4 n[KN];  // the one-and-only HBM read of neigh: coalesced, kept in regs
        #pragma unroll
        for (int j = 0; j < KN; ++j) n[j] = nb[j * (EMB / 4) + lane];

        float sc[KN];
        #pragma unroll
        for (int j = 0; j < KN; ++j) {
            float v = dot4(p4, n[j]);
            v += __shfl_xor(v, 1);
            v += __shfl_xor(v, 2);
            v += __shfl_xor(v, 4);
            v += __shfl_xor(v, 8);
            v += __shfl_xor(v, 16);
            v += __shfl_xor(v, 32);
            sc[j] = v;  // every lane has the full dot
        }
        // log-confidence + scale
        const float4* cf4p = reinterpret_cast<const float4*>(conf + (size_t)grow * KN);
        #pragma unroll
        for (int jj = 0; jj < 4; ++jj) {
            const float4 cf = cf4p[jj];
            sc[jj * 4 + 0] = sc[jj * 4 + 0] * 0.125f + __logf(cf.x + 1e-8f);
            sc[jj * 4 + 1] = sc[jj * 4 + 1] * 0.125f + __logf(cf.y + 1e-8f);
            sc[jj * 4 + 2] = sc[jj * 4 + 2] * 0.125f + __logf(cf.z + 1e-8f);
            sc[jj * 4 + 3] = sc[jj * 4 + 3] * 0.125f + __logf(cf.w + 1e-8f);
        }
        float mx = sc[0];
        #pragma unroll
        for (int j = 1; j < KN; ++j) mx = fmaxf(mx, sc[j]);
        float sum = 0.f;
        #pragma unroll
        for (int j = 0; j < KN; ++j) {
            const float e = __expf(sc[j] - mx);
            sc[j] = e;
            sum += e;
        }
        const float inv = 1.0f / sum;
        float4 ctx = make_float4(0.f, 0.f, 0.f, 0.f);
        #pragma unroll
        for (int j = 0; j < KN; ++j) {
            const float a = sc[j] * inv;
            ctx.x = fmaf(a, n[j].x, ctx.x);
            ctx.y = fmaf(a, n[j].y, ctx.y);
            ctx.z = fmaf(a, n[j].z, ctx.z);
            ctx.w = fmaf(a, n[j].w, ctx.w);
        }
        *reinterpret_cast<float4*>(&x_lds[r][lane * 4]) = ctx;
    }
    __syncthreads();

    // ---- Phase G: gate GEMM [16 rows x 512] x Wg^T -> sigmoid -> blend ----
    // thread tile: 2 outputs (o0, o0+128) x 8 rows
    const int o0 = t & 127;
    const int rh = t >> 7;  // 0..1 -> rows rh*8..rh*8+7
    float acc0[8], acc1[8];
    #pragma unroll
    for (int r = 0; r < 8; ++r) { acc0[r] = 0.f; acc1[r] = 0.f; }

    #pragma unroll 1
    for (int part = 0; part < 2; ++part) {
        const float* xbase = part ? &x_lds[0][0] : &c_lds[0][0];
        const float4* wg0 = reinterpret_cast<const float4*>(Wg + (size_t)o0 * (2 * EMB) + part * EMB);
        const float4* wg1 = reinterpret_cast<const float4*>(Wg + (size_t)(o0 + 128) * (2 * EMB) + part * EMB);
        for (int i = 0; i < EMB / 4; ++i) {
            const float4 w0 = wg0[i];
            const float4 w1 = wg1[i];
            #pragma unroll
            for (int r = 0; r < 8; ++r) {
                const float4 x4 = *reinterpret_cast<const float4*>(xbase + (rh * 8 + r) * EMB + i * 4);
                acc0[r] += dot4(w0, x4);
                acc1[r] += dot4(w1, x4);
            }
        }
    }

    // ---- Epilogue: sigmoid gate, blend, valid mask, store ----
    const float b0 = Wgb[o0];
    const float b1 = Wgb[o0 + 128];
    #pragma unroll
    for (int r = 0; r < 8; ++r) {
        const int row = rh * 8 + r;
        const int grow = rowBase + row;
        const int v = valid[grow];
        const float c0 = c_lds[row][o0];
        const float c1 = c_lds[row][o0 + 128];
        const float x0 = x_lds[row][o0];
        const float x1 = x_lds[row][o0 + 128];
        const float g0 = 1.0f / (1.0f + __expf(-(acc0[r] + b0)));
        const float g1 = 1.0f / (1.0f + __expf(-(acc1[r] + b1)));
        const float y0 = v ? (g0 * c0 + (1.0f - g0) * x0) : c0;
        const float y1 = v ? (g1 * c1 + (1.0f - g1) * x1) : c1;
        out[(size_t)grow * EMB + o0] = y0;
        out[(size_t)grow * EMB + o0 + 128] = y1;
    }
}

extern "C" void kernel_launch(void* const* d_in, const int* in_sizes, int n_in,
                              void* d_out, int out_size, void* d_ws, size_t ws_size,
                              hipStream_t stream) {
    const float* center = (const float*)d_in[0];
    const float* neigh  = (const float*)d_in[1];
    const float* conf   = (const float*)d_in[2];
    const int*   valid  = (const int*)d_in[3];
    const float* Wq     = (const float*)d_in[4];
    const float* Wk     = (const float*)d_in[5];
    const float* Wg     = (const float*)d_in[6];
    const float* Wgb    = (const float*)d_in[7];
    float* out = (float*)d_out;

    const int B = in_sizes[0] / EMB;      // 65536
    const int grid = B / ROWS;            // 4096 blocks of 256 threads

    fused_neigh_attn<<<grid, NT, 0, stream>>>(center, neigh, conf, valid,
                                              Wq, Wk, Wg, Wgb, out);
}